// Round 1
// baseline (471.461 us; speedup 1.0000x reference)
//
#include <hip/hip_runtime.h>
#include <stdint.h>

typedef uint16_t u16;

#define NB   16
#define NN   512
#define FF   625      // H*W
#define FH   937      // int(625*1.5)
#define ROWS 8192     // NB*NN
#define KS1  1280     // pad of 625+625 concat (625 | pad to 640 | 625 | pad)
#define KS2  1920     // pad of 937+937 concat (937 | pad to 960 | 937 | pad)
#define NP1  1024     // Fh padded to 128-multiple
#define NP2  640      // F padded to 128-multiple

using frag_ab = __attribute__((ext_vector_type(8))) short;  // 8 bf16
using frag_cd = __attribute__((ext_vector_type(4))) float;  // 4 fp32

__device__ __forceinline__ u16 f32_bf16(float f) {
  union { float f; uint32_t u; } x; x.f = f;
  uint32_t r = x.u + 0x7fffu + ((x.u >> 16) & 1u);   // RNE
  return (u16)(r >> 16);
}
__device__ __forceinline__ float bf16_f32(u16 u) {
  union { uint32_t u; float f; } x; x.u = ((uint32_t)u) << 16;
  return x.f;
}
// async global->LDS, 16B per lane. LDS dest must be wave-uniform base; HW adds lane*16.
__device__ __forceinline__ void gload_lds16(const void* g, void* l) {
  __builtin_amdgcn_global_load_lds((__attribute__((address_space(1))) void*)g,
                                   (__attribute__((address_space(3))) void*)l,
                                   16, 0, 0);
}

// ---------------------------------------------------------------------------
// Kernel 1: per-row graph build. att filter -> candidates -> fp32 L1 distance
// -> accepted neighbor list + deg -> t1 gather-sum. Writes Xcat = [X | t1] bf16.
// ---------------------------------------------------------------------------
__global__ __launch_bounds__(256) void build_graph(
    const float* __restrict__ x4,   // [ROWS][625]
    const float* __restrict__ att,  // [ROWS]
    u16* __restrict__ Xcat,         // [ROWS][KS1] bf16
    u16* __restrict__ nbr,          // [ROWS][512]
    int* __restrict__ degbuf,       // [ROWS]
    float* __restrict__ invbuf)     // [ROWS]
{
  __shared__ float att_sh[512];
  __shared__ float Xi[640];
  __shared__ u16 cand[512];
  __shared__ u16 accj[512];
  __shared__ int ncand, nacc;

  const int tid = threadIdx.x;
  const int row = blockIdx.x;          // b*512 + i
  const int b = row >> 9;
  const int i = row & 511;
  const float* Xb = x4 + (size_t)b * NN * FF;

  att_sh[tid]       = att[b * NN + tid];
  att_sh[tid + 256] = att[b * NN + tid + 256];
  for (int f = tid; f < FF; f += 256) Xi[f] = Xb[(size_t)i * FF + f];
  if (tid == 0) { ncand = 0; nacc = 0; }
  __syncthreads();

  const float ai = att_sh[i];
  // candidate filter (cheap): |ai - aj| <= 0.05, j != i
  for (int j = tid; j < NN; j += 256) {
    if (j != i && fabsf(ai - att_sh[j]) <= 0.05f) {
      int p = atomicAdd(&ncand, 1);
      cand[p] = (u16)j;
    }
  }
  __syncthreads();

  // fp32 L1 distance only on candidates: one wave per candidate
  const int lane = tid & 63;
  const int wave = tid >> 6;
  const int nc = ncand;
  for (int c = wave; c < nc; c += 4) {
    const int j = cand[c];
    const float* Xj = Xb + (size_t)j * FF;
    float p = 0.f;
    for (int f = lane; f < FF; f += 64) p += fabsf(Xi[f] - Xj[f]);
    #pragma unroll
    for (int off = 32; off; off >>= 1) p += __shfl_xor(p, off, 64);
    if (lane == 0 && p <= 180.0f) {
      int q = atomicAdd(&nacc, 1);
      accj[q] = (u16)j;
    }
  }
  __syncthreads();

  const int na = nacc;
  const float inv = 1.0f / (float)(na + 1);
  for (int c = tid; c < na; c += 256) nbr[(size_t)row * 512 + c] = accj[c];
  if (tid == 0) { degbuf[row] = na; invbuf[row] = inv; }

  // t1 = (Xi + sum_j Xj) * inv ; write Xcat row: [X(625) pad(15) t1(625) pad(15)]
  for (int f = tid; f < 640; f += 256) {
    float xv = 0.f, t1 = 0.f;
    if (f < FF) {
      xv = Xi[f];
      float s = xv;
      for (int c = 0; c < na; ++c) s += Xb[(size_t)accj[c] * FF + f];
      t1 = s * inv;
    }
    Xcat[(size_t)row * KS1 + f]       = (f < FF) ? f32_bf16(xv) : (u16)0;
    Xcat[(size_t)row * KS1 + 640 + f] = (f < FF) ? f32_bf16(t1) : (u16)0;
  }
}

// ---------------------------------------------------------------------------
// Kernel 2: layer-2 gather: t2 = (h_i + sum_j h_j) * inv over same nbr lists.
// hcat row layout: [h(937) pad(23) t2(937) pad(23)]; h cols written by GEMM1.
// ---------------------------------------------------------------------------
__global__ __launch_bounds__(256) void gather2(
    u16* __restrict__ hcat,          // [ROWS][KS2] bf16
    const u16* __restrict__ nbr,
    const int* __restrict__ degbuf,
    const float* __restrict__ invbuf)
{
  __shared__ u16 accj[512];
  const int tid = threadIdx.x;
  const int row = blockIdx.x;
  const int b = row >> 9;
  const int na = degbuf[row];
  const float inv = invbuf[row];
  for (int c = tid; c < na; c += 256) accj[c] = nbr[(size_t)row * 512 + c];
  __syncthreads();

  const u16* hbat = hcat + (size_t)b * NN * KS2;
  const u16* hrow = hcat + (size_t)row * KS2;
  for (int f = tid; f < 960; f += 256) {
    float s = 0.f;
    if (f < FH) {
      s = bf16_f32(hrow[f]);
      for (int c = 0; c < na; ++c) s += bf16_f32(hbat[(size_t)accj[c] * KS2 + f]);
      s *= inv;
    }
    hcat[(size_t)row * KS2 + 960 + f] = (f < FH) ? f32_bf16(s) : (u16)0;
    if (f >= FH) hcat[(size_t)row * KS2 + f] = 0;  // zero pad cols 937..959
  }
}

// ---------------------------------------------------------------------------
// Weight converters: fp32 W[k][n] -> bf16 W^T[n][k] (padded, zero-filled),
// LDS-transposed so both read and write are coalesced.
// ---------------------------------------------------------------------------
__global__ __launch_bounds__(256) void convert_w1(const float* __restrict__ W1,
                                                  u16* __restrict__ Wt) {
  __shared__ float tile[32][33];
  const int kt = blockIdx.x, nt = blockIdx.y;
  const int tx = threadIdx.x & 31, ty = threadIdx.x >> 5;
  #pragma unroll
  for (int r = 0; r < 4; ++r) {
    int k = kt * 32 + ty + r * 8;
    int n = nt * 32 + tx;
    float v = 0.f;
    int c = -1, kk = 0;
    if (k < 625) { c = 0; kk = k; }
    else if (k >= 640 && k < 1265) { c = 1; kk = k - 640; }
    if (c >= 0 && n < FH) v = W1[((size_t)c * 625 + kk) * FH + n];
    tile[ty + r * 8][tx] = v;
  }
  __syncthreads();
  #pragma unroll
  for (int r = 0; r < 4; ++r) {
    int n = nt * 32 + ty + r * 8;
    int k = kt * 32 + tx;
    Wt[(size_t)n * KS1 + k] = f32_bf16(tile[tx][ty + r * 8]);
  }
}

__global__ __launch_bounds__(256) void convert_w2(const float* __restrict__ W2,
                                                  u16* __restrict__ Wt) {
  __shared__ float tile[32][33];
  const int kt = blockIdx.x, nt = blockIdx.y;
  const int tx = threadIdx.x & 31, ty = threadIdx.x >> 5;
  #pragma unroll
  for (int r = 0; r < 4; ++r) {
    int k = kt * 32 + ty + r * 8;
    int n = nt * 32 + tx;
    float v = 0.f;
    int c = -1, kk = 0;
    if (k < 937) { c = 0; kk = k; }
    else if (k >= 960 && k < 1897) { c = 1; kk = k - 960; }
    if (c >= 0 && n < FF) v = W2[((size_t)c * 937 + kk) * FF + n];
    tile[ty + r * 8][tx] = v;
  }
  __syncthreads();
  #pragma unroll
  for (int r = 0; r < 4; ++r) {
    int n = nt * 32 + ty + r * 8;
    int k = kt * 32 + tx;
    Wt[(size_t)n * KS2 + k] = f32_bf16(tile[tx][ty + r * 8]);
  }
}

// ---------------------------------------------------------------------------
// m97-style bf16 GEMM: A [M][KS] row-major, Bt [Npad][KS] (= B^T), 128x128
// block tile, BK=32, 4 waves each 64x64 (4x4 of 16x16x32 MFMA), single-buffer
// LDS via global_load_lds width=16. Epilogue: +bias, relu, store bf16 or fp32.
// ---------------------------------------------------------------------------
template <int KS, int NREAL, int LDC, bool OUT_BF16>
__global__ __launch_bounds__(256) void gemm_bt(
    const u16* __restrict__ A, const u16* __restrict__ Bt,
    const float* __restrict__ bias, void* __restrict__ C)
{
  __shared__ __align__(16) u16 Ash[128 * 32];
  __shared__ __align__(16) u16 Bsh[128 * 32];

  const int tid  = threadIdx.x;
  const int lane = tid & 63;
  const int wave = tid >> 6;
  const int wm = wave & 1, wn = wave >> 1;
  const int q = lane >> 4, l16 = lane & 15;
  const int m0 = blockIdx.x * 128;
  const int n0 = blockIdx.y * 128;

  // staging addresses: round r covers idx = r*256+tid; row=idx>>2, c=idx&3
  const int i0 = tid, i1 = 256 + tid;
  const u16* pa0 = A + (size_t)(m0 + (i0 >> 2)) * KS + (i0 & 3) * 8;
  const u16* pa1 = A + (size_t)(m0 + (i1 >> 2)) * KS + (i1 & 3) * 8;
  const u16* pb0 = Bt + (size_t)(n0 + (i0 >> 2)) * KS + (i0 & 3) * 8;
  const u16* pb1 = Bt + (size_t)(n0 + (i1 >> 2)) * KS + (i1 & 3) * 8;
  const int wbase = (tid & 192) * 8;             // wave-uniform LDS base (u16 units)
  u16* la0 = &Ash[wbase];       u16* la1 = &Ash[2048 + wbase];
  u16* lb0 = &Bsh[wbase];       u16* lb1 = &Bsh[2048 + wbase];

  // fragment LDS pointers (constant across K loop)
  const frag_ab* fA[4]; const frag_ab* fB[4];
  #pragma unroll
  for (int mi = 0; mi < 4; ++mi)
    fA[mi] = (const frag_ab*)&Ash[(wm * 64 + mi * 16 + l16) * 32 + q * 8];
  #pragma unroll
  for (int ni = 0; ni < 4; ++ni)
    fB[ni] = (const frag_ab*)&Bsh[(wn * 64 + ni * 16 + l16) * 32 + q * 8];

  frag_cd acc[4][4] = {};

  constexpr int KT = KS / 32;
  for (int kt = 0; kt < KT; ++kt) {
    __syncthreads();                 // previous tile's ds_reads done
    gload_lds16(pa0, la0); gload_lds16(pa1, la1);
    gload_lds16(pb0, lb0); gload_lds16(pb1, lb1);
    pa0 += 32; pa1 += 32; pb0 += 32; pb1 += 32;
    __syncthreads();                 // drains vmcnt -> tile visible

    frag_ab av[4], bv[4];
    #pragma unroll
    for (int mi = 0; mi < 4; ++mi) av[mi] = *fA[mi];
    #pragma unroll
    for (int ni = 0; ni < 4; ++ni) bv[ni] = *fB[ni];
    #pragma unroll
    for (int mi = 0; mi < 4; ++mi)
      #pragma unroll
      for (int ni = 0; ni < 4; ++ni)
        acc[mi][ni] = __builtin_amdgcn_mfma_f32_16x16x32_bf16(
            av[mi], bv[ni], acc[mi][ni], 0, 0, 0);
  }

  // epilogue: C/D layout col=lane&15, row=(lane>>4)*4+reg
  #pragma unroll
  for (int ni = 0; ni < 4; ++ni) {
    const int col = n0 + wn * 64 + ni * 16 + l16;
    const bool ok = (col < NREAL);
    const float bvv = ok ? bias[col] : 0.f;
    #pragma unroll
    for (int mi = 0; mi < 4; ++mi) {
      #pragma unroll
      for (int r = 0; r < 4; ++r) {
        const int rowg = m0 + wm * 64 + mi * 16 + q * 4 + r;
        float v = acc[mi][ni][r] + bvv;
        v = fmaxf(v, 0.f);
        if (ok) {
          if (OUT_BF16)
            ((u16*)C)[(size_t)rowg * LDC + col] = f32_bf16(v);
          else
            ((float*)C)[(size_t)rowg * LDC + col] = v;
        }
      }
    }
  }
}

// ---------------------------------------------------------------------------
extern "C" void kernel_launch(void* const* d_in, const int* in_sizes, int n_in,
                              void* d_out, int out_size, void* d_ws, size_t ws_size,
                              hipStream_t stream) {
  const float* x4  = (const float*)d_in[0];
  const float* att = (const float*)d_in[1];
  const float* W1  = (const float*)d_in[2];
  const float* b1  = (const float*)d_in[3];
  const float* W2  = (const float*)d_in[4];
  const float* b2  = (const float*)d_in[5];
  float* out = (float*)d_out;

  char* ws = (char*)d_ws;
  u16* Xcat = (u16*)ws;  ws += (size_t)ROWS * KS1 * 2;   // 20.97 MB
  u16* hcat = (u16*)ws;  ws += (size_t)ROWS * KS2 * 2;   // 31.46 MB
  u16* W1t  = (u16*)ws;  ws += (size_t)NP1 * KS1 * 2;    //  2.62 MB
  u16* W2t  = (u16*)ws;  ws += (size_t)NP2 * KS2 * 2;    //  2.46 MB
  u16* nbr  = (u16*)ws;  ws += (size_t)ROWS * 512 * 2;   //  8.39 MB
  int*   deg = (int*)ws;   ws += (size_t)ROWS * 4;
  float* inv = (float*)ws; ws += (size_t)ROWS * 4;

  convert_w1<<<dim3(KS1 / 32, NP1 / 32), 256, 0, stream>>>(W1, W1t);
  convert_w2<<<dim3(KS2 / 32, NP2 / 32), 256, 0, stream>>>(W2, W2t);
  build_graph<<<dim3(ROWS), 256, 0, stream>>>(x4, att, Xcat, nbr, deg, inv);
  gemm_bt<KS1, FH, KS2, true><<<dim3(64, NP1 / 128), 256, 0, stream>>>(
      Xcat, W1t, b1, (void*)hcat);
  gather2<<<dim3(ROWS), 256, 0, stream>>>(hcat, nbr, deg, inv);
  gemm_bt<KS2, FF, FF, false><<<dim3(64, NP2 / 128), 256, 0, stream>>>(
      hcat, W2t, b2, (void*)out);
}

// Round 2
// 271.505 us; speedup vs baseline: 1.7365x; 1.7365x over previous
//
#include <hip/hip_runtime.h>
#include <stdint.h>

typedef uint16_t u16;
typedef __attribute__((ext_vector_type(4))) float f32x4;
typedef __attribute__((ext_vector_type(4))) unsigned short us4;
typedef __attribute__((ext_vector_type(8))) unsigned short us8;

#define NB   16
#define NN   512
#define FF   625      // H*W
#define FH   937      // int(625*1.5)
#define ROWS 8192     // NB*NN
#define KS1  1280     // [X(625) pad->640 | t1(625) pad->640]
#define KS2  1920     // [h(937) pad->960 | t2(937) pad->960]
#define NP1  1024     // Fh padded to 128
#define NP2  640      // F padded to 128
#define F4   160      // 640/4 float4 slots per padded X row

using frag_ab = __attribute__((ext_vector_type(8))) short;  // 8 bf16
using frag_cd = __attribute__((ext_vector_type(4))) float;  // 4 fp32

__device__ __forceinline__ u16 f32_bf16(float f) {
  union { float f; uint32_t u; } x; x.f = f;
  uint32_t r = x.u + 0x7fffu + ((x.u >> 16) & 1u);   // RNE
  return (u16)(r >> 16);
}
__device__ __forceinline__ float bf16_f32(u16 u) {
  union { uint32_t u; float f; } x; x.u = ((uint32_t)u) << 16;
  return x.f;
}
__device__ __forceinline__ void gload_lds16(const void* g, void* l) {
  __builtin_amdgcn_global_load_lds((__attribute__((address_space(1))) void*)g,
                                   (__attribute__((address_space(3))) void*)l,
                                   16, 0, 0);
}

// ---------------------------------------------------------------------------
// pad_x: x4 [ROWS][625] fp32 -> Xpad [ROWS][160] f32x4 (zero pad) and
// Xcat bf16 cols 0..639.
// ---------------------------------------------------------------------------
__global__ __launch_bounds__(256) void pad_x(const float* __restrict__ x4,
                                             f32x4* __restrict__ Xpad,
                                             u16* __restrict__ Xcat) {
  const int idx = blockIdx.x * 256 + threadIdx.x;      // ROWS*160 total
  if (idx >= ROWS * F4) return;
  const int row = idx / F4;
  const int k4 = idx - row * F4;
  f32x4 v;
  us4 o;
  #pragma unroll
  for (int t = 0; t < 4; ++t) {
    const int f = k4 * 4 + t;
    float x = (f < FF) ? x4[(size_t)row * FF + f] : 0.f;
    v[t] = x;
    o[t] = f32_bf16(x);
  }
  Xpad[idx] = v;
  *(us4*)(Xcat + (size_t)row * KS1 + k4 * 4) = o;
}

// ---------------------------------------------------------------------------
// build_graph v2: per-row block. att filter -> candidates; one wave per
// candidate, float4 distance; accepted Xj accumulated in registers (single
// pass over L2); combine wave partials in LDS; write t1 bf16 + nbr/deg/inv.
// ---------------------------------------------------------------------------
__global__ __launch_bounds__(256) void build_graph(
    const f32x4* __restrict__ Xpad,  // [ROWS][160]
    const float* __restrict__ att,   // [ROWS]
    u16* __restrict__ Xcat,          // [ROWS][KS1] bf16 (t1 half written here)
    u16* __restrict__ nbr,           // [ROWS][512]
    int* __restrict__ degbuf,
    float* __restrict__ invbuf)
{
  __shared__ float att_sh[512];
  __shared__ f32x4 Xi4[F4];
  __shared__ u16 cand[512];
  __shared__ u16 accj[512];
  __shared__ f32x4 wsum[4][F4];
  __shared__ int ncand, nacc;

  const int tid = threadIdx.x;
  const int row = blockIdx.x;
  const int b = row >> 9;
  const int i = row & 511;
  const f32x4* Xb4 = Xpad + (size_t)b * NN * F4;

  att_sh[tid]       = att[b * NN + tid];
  att_sh[tid + 256] = att[b * NN + tid + 256];
  if (tid < F4) Xi4[tid] = Xb4[(size_t)i * F4 + tid];
  if (tid == 0) { ncand = 0; nacc = 0; }
  __syncthreads();

  const float ai = att_sh[i];
  for (int j = tid; j < NN; j += 256) {
    if (j != i && fabsf(ai - att_sh[j]) <= 0.05f) {
      int p = atomicAdd(&ncand, 1);
      cand[p] = (u16)j;
    }
  }
  __syncthreads();

  const int lane = tid & 63;
  const int wave = tid >> 6;
  const int nc = ncand;

  const f32x4 zero = {0.f, 0.f, 0.f, 0.f};
  f32x4 a0 = Xi4[lane];
  f32x4 a1 = Xi4[64 + lane];
  f32x4 a2 = (lane < 32) ? Xi4[128 + lane] : zero;
  f32x4 s0 = zero, s1 = zero, s2 = zero;

  for (int c = wave; c < nc; c += 4) {
    const int j = cand[c];
    const f32x4* Xj = Xb4 + (size_t)j * F4;
    f32x4 x0 = Xj[lane];
    f32x4 x1 = Xj[64 + lane];
    f32x4 x2 = (lane < 32) ? Xj[128 + lane] : zero;
    f32x4 d0 = a0 - x0, d1 = a1 - x1, d2 = a2 - x2;
    float p = 0.f;
    #pragma unroll
    for (int t = 0; t < 4; ++t)
      p += fabsf(d0[t]) + fabsf(d1[t]) + fabsf(d2[t]);
    #pragma unroll
    for (int off = 32; off; off >>= 1) p += __shfl_xor(p, off, 64);
    if (p <= 180.0f) {                       // wave-uniform after butterfly
      s0 += x0; s1 += x1; s2 += x2;
      if (lane == 0) { int q = atomicAdd(&nacc, 1); accj[q] = (u16)j; }
    }
  }
  wsum[wave][lane] = s0;
  wsum[wave][64 + lane] = s1;
  if (lane < 32) wsum[wave][128 + lane] = s2;
  __syncthreads();

  const int na = nacc;
  const float inv = 1.0f / (float)(na + 1);
  for (int c = tid; c < na; c += 256) nbr[(size_t)row * 512 + c] = accj[c];
  if (tid == 0) { degbuf[row] = na; invbuf[row] = inv; }

  for (int k = tid; k < F4; k += 256) {      // threads 0..159
    f32x4 t = Xi4[k];
    #pragma unroll
    for (int w = 0; w < 4; ++w) t += wsum[w][k];
    us4 o;
    #pragma unroll
    for (int s = 0; s < 4; ++s) o[s] = f32_bf16(t[s] * inv);
    *(us4*)(Xcat + (size_t)row * KS1 + 640 + k * 4) = o;
  }
}

// ---------------------------------------------------------------------------
// gather2 v2: t2 = (h_i + sum_j h_j) * inv over cached nbr lists, us8 loads,
// c-loop split across 2 thread-groups, LDS combine. Also zeroes h pad cols.
// ---------------------------------------------------------------------------
__global__ __launch_bounds__(256) void gather2(
    u16* __restrict__ hcat,          // [ROWS][KS2] bf16
    const u16* __restrict__ nbr,
    const int* __restrict__ degbuf,
    const float* __restrict__ invbuf)
{
  __shared__ u16 accj[512];
  __shared__ float hsum[2][960];

  const int tid = threadIdx.x;
  const int row = blockIdx.x;
  const int b = row >> 9;
  const int na = degbuf[row];
  const float inv = invbuf[row];
  for (int c = tid; c < na; c += 256) accj[c] = nbr[(size_t)row * 512 + c];
  __syncthreads();

  const int g = tid >> 7;            // group 0/1
  const int slot = tid & 127;        // us8 slot (8 cols), active < 120
  const u16* hbat = hcat + (size_t)b * NN * KS2;

  float s[8] = {0,0,0,0,0,0,0,0};
  if (slot < 120) {
    for (int c = g; c < na; c += 2) {
      const us8 hv = *(const us8*)(hbat + (size_t)accj[c] * KS2 + slot * 8);
      #pragma unroll
      for (int t = 0; t < 8; ++t) s[t] += bf16_f32(hv[t]);
    }
    #pragma unroll
    for (int t = 0; t < 8; ++t) hsum[g][slot * 8 + t] = s[t];
  }
  __syncthreads();

  // zero h pad cols 937..959 (read side of these cols is discarded everywhere)
  if (tid < 23) hcat[(size_t)row * KS2 + FH + tid] = 0;

  const u16* hrow = hcat + (size_t)row * KS2;
  for (int k = tid; k < 120; k += 256) {     // threads 0..119
    const us8 hv = *(const us8*)(hrow + k * 8);
    us8 o;
    #pragma unroll
    for (int t = 0; t < 8; ++t) {
      const int col = k * 8 + t;
      float v = (bf16_f32(hv[t]) + hsum[0][col] + hsum[1][col]) * inv;
      o[t] = (col < FH) ? f32_bf16(v) : (u16)0;
    }
    *(us8*)(hcat + (size_t)row * KS2 + 960 + k * 8) = o;
  }
}

// ---------------------------------------------------------------------------
// Weight converters (unchanged): fp32 W[k][n] -> bf16 W^T[n][k] padded.
// ---------------------------------------------------------------------------
__global__ __launch_bounds__(256) void convert_w1(const float* __restrict__ W1,
                                                  u16* __restrict__ Wt) {
  __shared__ float tile[32][33];
  const int kt = blockIdx.x, nt = blockIdx.y;
  const int tx = threadIdx.x & 31, ty = threadIdx.x >> 5;
  #pragma unroll
  for (int r = 0; r < 4; ++r) {
    int k = kt * 32 + ty + r * 8;
    int n = nt * 32 + tx;
    float v = 0.f;
    int c = -1, kk = 0;
    if (k < 625) { c = 0; kk = k; }
    else if (k >= 640 && k < 1265) { c = 1; kk = k - 640; }
    if (c >= 0 && n < FH) v = W1[((size_t)c * 625 + kk) * FH + n];
    tile[ty + r * 8][tx] = v;
  }
  __syncthreads();
  #pragma unroll
  for (int r = 0; r < 4; ++r) {
    int n = nt * 32 + ty + r * 8;
    int k = kt * 32 + tx;
    Wt[(size_t)n * KS1 + k] = f32_bf16(tile[tx][ty + r * 8]);
  }
}

__global__ __launch_bounds__(256) void convert_w2(const float* __restrict__ W2,
                                                  u16* __restrict__ Wt) {
  __shared__ float tile[32][33];
  const int kt = blockIdx.x, nt = blockIdx.y;
  const int tx = threadIdx.x & 31, ty = threadIdx.x >> 5;
  #pragma unroll
  for (int r = 0; r < 4; ++r) {
    int k = kt * 32 + ty + r * 8;
    int n = nt * 32 + tx;
    float v = 0.f;
    int c = -1, kk = 0;
    if (k < 937) { c = 0; kk = k; }
    else if (k >= 960 && k < 1897) { c = 1; kk = k - 960; }
    if (c >= 0 && n < FF) v = W2[((size_t)c * 937 + kk) * FF + n];
    tile[ty + r * 8][tx] = v;
  }
  __syncthreads();
  #pragma unroll
  for (int r = 0; r < 4; ++r) {
    int n = nt * 32 + ty + r * 8;
    int k = kt * 32 + tx;
    Wt[(size_t)n * KS2 + k] = f32_bf16(tile[tx][ty + r * 8]);
  }
}

// ---------------------------------------------------------------------------
// m97-style bf16 GEMM (unchanged): A [M][KS], Bt [Npad][KS], 128x128 tile.
// ---------------------------------------------------------------------------
template <int KS, int NREAL, int LDC, bool OUT_BF16>
__global__ __launch_bounds__(256) void gemm_bt(
    const u16* __restrict__ A, const u16* __restrict__ Bt,
    const float* __restrict__ bias, void* __restrict__ C)
{
  __shared__ __align__(16) u16 Ash[128 * 32];
  __shared__ __align__(16) u16 Bsh[128 * 32];

  const int tid  = threadIdx.x;
  const int lane = tid & 63;
  const int wave = tid >> 6;
  const int wm = wave & 1, wn = wave >> 1;
  const int q = lane >> 4, l16 = lane & 15;
  const int m0 = blockIdx.x * 128;
  const int n0 = blockIdx.y * 128;

  const int i0 = tid, i1 = 256 + tid;
  const u16* pa0 = A + (size_t)(m0 + (i0 >> 2)) * KS + (i0 & 3) * 8;
  const u16* pa1 = A + (size_t)(m0 + (i1 >> 2)) * KS + (i1 & 3) * 8;
  const u16* pb0 = Bt + (size_t)(n0 + (i0 >> 2)) * KS + (i0 & 3) * 8;
  const u16* pb1 = Bt + (size_t)(n0 + (i1 >> 2)) * KS + (i1 & 3) * 8;
  const int wbase = (tid & 192) * 8;
  u16* la0 = &Ash[wbase];       u16* la1 = &Ash[2048 + wbase];
  u16* lb0 = &Bsh[wbase];       u16* lb1 = &Bsh[2048 + wbase];

  const frag_ab* fA[4]; const frag_ab* fB[4];
  #pragma unroll
  for (int mi = 0; mi < 4; ++mi)
    fA[mi] = (const frag_ab*)&Ash[(wm * 64 + mi * 16 + l16) * 32 + q * 8];
  #pragma unroll
  for (int ni = 0; ni < 4; ++ni)
    fB[ni] = (const frag_ab*)&Bsh[(wn * 64 + ni * 16 + l16) * 32 + q * 8];

  frag_cd acc[4][4] = {};

  constexpr int KT = KS / 32;
  for (int kt = 0; kt < KT; ++kt) {
    __syncthreads();
    gload_lds16(pa0, la0); gload_lds16(pa1, la1);
    gload_lds16(pb0, lb0); gload_lds16(pb1, lb1);
    pa0 += 32; pa1 += 32; pb0 += 32; pb1 += 32;
    __syncthreads();

    frag_ab av[4], bv[4];
    #pragma unroll
    for (int mi = 0; mi < 4; ++mi) av[mi] = *fA[mi];
    #pragma unroll
    for (int ni = 0; ni < 4; ++ni) bv[ni] = *fB[ni];
    #pragma unroll
    for (int mi = 0; mi < 4; ++mi)
      #pragma unroll
      for (int ni = 0; ni < 4; ++ni)
        acc[mi][ni] = __builtin_amdgcn_mfma_f32_16x16x32_bf16(
            av[mi], bv[ni], acc[mi][ni], 0, 0, 0);
  }

  #pragma unroll
  for (int ni = 0; ni < 4; ++ni) {
    const int col = n0 + wn * 64 + ni * 16 + l16;
    const bool ok = (col < NREAL);
    const float bvv = ok ? bias[col] : 0.f;
    #pragma unroll
    for (int mi = 0; mi < 4; ++mi) {
      #pragma unroll
      for (int r = 0; r < 4; ++r) {
        const int rowg = m0 + wm * 64 + mi * 16 + q * 4 + r;
        float v = acc[mi][ni][r] + bvv;
        v = fmaxf(v, 0.f);
        if (ok) {
          if (OUT_BF16)
            ((u16*)C)[(size_t)rowg * LDC + col] = f32_bf16(v);
          else
            ((float*)C)[(size_t)rowg * LDC + col] = v;
        }
      }
    }
  }
}

// ---------------------------------------------------------------------------
extern "C" void kernel_launch(void* const* d_in, const int* in_sizes, int n_in,
                              void* d_out, int out_size, void* d_ws, size_t ws_size,
                              hipStream_t stream) {
  const float* x4  = (const float*)d_in[0];
  const float* att = (const float*)d_in[1];
  const float* W1  = (const float*)d_in[2];
  const float* b1  = (const float*)d_in[3];
  const float* W2  = (const float*)d_in[4];
  const float* b2  = (const float*)d_in[5];
  float* out = (float*)d_out;

  char* ws = (char*)d_ws;
  f32x4* Xpad = (f32x4*)ws; ws += (size_t)ROWS * F4 * 16;   // 20.97 MB
  u16* Xcat = (u16*)ws;  ws += (size_t)ROWS * KS1 * 2;      // 20.97 MB
  u16* hcat = (u16*)ws;  ws += (size_t)ROWS * KS2 * 2;      // 31.46 MB
  u16* W1t  = (u16*)ws;  ws += (size_t)NP1 * KS1 * 2;       //  2.62 MB
  u16* W2t  = (u16*)ws;  ws += (size_t)NP2 * KS2 * 2;       //  2.46 MB
  u16* nbr  = (u16*)ws;  ws += (size_t)ROWS * 512 * 2;      //  8.39 MB
  int*   deg = (int*)ws;   ws += (size_t)ROWS * 4;
  float* inv = (float*)ws; ws += (size_t)ROWS * 4;

  convert_w1<<<dim3(KS1 / 32, NP1 / 32), 256, 0, stream>>>(W1, W1t);
  convert_w2<<<dim3(KS2 / 32, NP2 / 32), 256, 0, stream>>>(W2, W2t);
  pad_x<<<dim3((ROWS * F4 + 255) / 256), 256, 0, stream>>>(x4, Xpad, Xcat);
  build_graph<<<dim3(ROWS), 256, 0, stream>>>(Xpad, att, Xcat, nbr, deg, inv);
  gemm_bt<KS1, FH, KS2, true><<<dim3(64, NP1 / 128), 256, 0, stream>>>(
      Xcat, W1t, b1, (void*)hcat);
  gather2<<<dim3(ROWS), 256, 0, stream>>>(hcat, nbr, deg, inv);
  gemm_bt<KS2, FF, FF, false><<<dim3(64, NP2 / 128), 256, 0, stream>>>(
      hcat, W2t, b2, (void*)out);
}